// Round 1
// baseline (195.294 us; speedup 1.0000x reference)
//
#include <hip/hip_runtime.h>

typedef unsigned short u16;
typedef __attribute__((ext_vector_type(8))) __bf16 bf16x8;
typedef __attribute__((ext_vector_type(4))) float f32x4;
typedef __attribute__((ext_vector_type(4))) int i32x4;

#define MFMA16(a, b, c) __builtin_amdgcn_mfma_f32_16x16x32_bf16(a, b, c, 0, 0, 0)

__device__ __forceinline__ u16 f2b(float f) {
  __bf16 h = (__bf16)f;
  return __builtin_bit_cast(u16, h);
}

// global -> LDS direct (wave-uniform LDS base + lane*16; global addr per-lane)
__device__ __forceinline__ void gl_lds16(const void* g, void* l) {
  __builtin_amdgcn_global_load_lds(
      (const __attribute__((address_space(1))) void*)g,
      (__attribute__((address_space(3))) void*)l, 16, 0, 0);
}

__device__ __forceinline__ bf16x8 ldf(const void* p) {
  return __builtin_bit_cast(bf16x8, *(const i32x4*)p);
}

// ---------------- f32 -> bf16 convert ----------------
__global__ __launch_bounds__(256) void cvt_kernel(const float4* __restrict__ in,
                                                  ushort4* __restrict__ out, int n4) {
  for (int i = blockIdx.x * blockDim.x + threadIdx.x; i < n4; i += gridDim.x * blockDim.x) {
    float4 v = in[i];
    ushort4 o;
    o.x = f2b(v.x); o.y = f2b(v.y); o.z = f2b(v.z); o.w = f2b(v.w);
    out[i] = o;
  }
}

// ---------------- GEMM: C[m][n] = sum_k A[m][k]*B[n][k] (+bias) ----------------
// m97 structure: BM=BN=128, BK=32, 4 waves (2x2), global_load_lds width 16.
// EPI=0: QKV epilogue -> q_s/k_s [bh][t][64] bf16, v transposed -> vt_s [bh][64][t] bf16
// EPI=1: proj epilogue -> f32 out [m][N]
template <int EPI>
__global__ __launch_bounds__(256) void gemm_bt(
    const u16* __restrict__ A, const u16* __restrict__ B,
    const float* __restrict__ bias, int M, int N, int K,
    u16* __restrict__ q_s, u16* __restrict__ k_s, u16* __restrict__ vt_s,
    float* __restrict__ outf) {
  __shared__ __align__(16) u16 As[128 * 32];
  __shared__ __align__(16) u16 Bs[128 * 32];
  const int tid = threadIdx.x;
  const int w = tid >> 6, l = tid & 63;
  const int lo = l & 15, hi = l >> 4;
  const int wr = w >> 1, wc = w & 1;
  const int bm0 = blockIdx.y * 128, bn0 = blockIdx.x * 128;
  const size_t Kb = (size_t)K * 2;

  f32x4 acc[4][4] = {};
  const char* Ab = (const char*)A;
  const char* Bb = (const char*)B;

  for (int kt = 0; kt < K; kt += 32) {
    __syncthreads();  // previous iter's ds_reads done before overwrite
#pragma unroll
    for (int i = 0; i < 2; ++i) {
      int c = w * 2 + i;                 // chunk 0..7 (1KB each)
      int row = c * 16 + (l >> 2);       // 16 rows / chunk (64B rows)
      int colb = (l & 3) * 16;
      gl_lds16(Ab + (size_t)(bm0 + row) * Kb + (size_t)kt * 2 + colb, (char*)As + c * 1024);
      gl_lds16(Bb + (size_t)(bn0 + row) * Kb + (size_t)kt * 2 + colb, (char*)Bs + c * 1024);
    }
    __syncthreads();  // vmcnt(0) drain -> tiles ready
    bf16x8 bfr[4];
#pragma unroll
    for (int nf = 0; nf < 4; ++nf)
      bfr[nf] = ldf((const char*)Bs + (wc * 64 + nf * 16 + lo) * 64 + hi * 16);
#pragma unroll
    for (int mf = 0; mf < 4; ++mf) {
      bf16x8 afr = ldf((const char*)As + (wr * 64 + mf * 16 + lo) * 64 + hi * 16);
#pragma unroll
      for (int nf = 0; nf < 4; ++nf) acc[mf][nf] = MFMA16(afr, bfr[nf], acc[mf][nf]);
    }
  }

  // Epilogue. C/D layout: col = lo, row = hi*4 + reg (m89/m91-verified).
#pragma unroll
  for (int nf = 0; nf < 4; ++nf) {
    int col = bn0 + wc * 64 + nf * 16 + lo;
    float bv = bias[col];
    if (EPI == 0) {
      int seg = col / 768;           // 0=q 1=k 2=v (BN=128 divides 768 -> uniform/block)
      int cs = col - seg * 768;
      int h = cs >> 6, d = cs & 63;
      u16* dst = (seg == 0) ? q_s : k_s;
#pragma unroll
      for (int mf = 0; mf < 4; ++mf) {
        int m0 = bm0 + wr * 64 + mf * 16 + hi * 4;
        int bb = m0 >> 10, t0 = m0 & 1023;
        size_t bh = (size_t)(bb * 12 + h);
        if (seg < 2) {
#pragma unroll
          for (int r = 0; r < 4; ++r)
            dst[(bh * 1024 + t0 + r) * 64 + d] = f2b(acc[mf][nf][r] + bv);
        } else {  // v transposed: 4 consecutive t -> one 8B store
          ushort4 pk;
          pk.x = f2b(acc[mf][nf][0] + bv);
          pk.y = f2b(acc[mf][nf][1] + bv);
          pk.z = f2b(acc[mf][nf][2] + bv);
          pk.w = f2b(acc[mf][nf][3] + bv);
          *(ushort4*)&vt_s[(bh * 64 + d) * 1024 + t0] = pk;
        }
      }
    } else {
#pragma unroll
      for (int mf = 0; mf < 4; ++mf) {
        int m0 = bm0 + wr * 64 + mf * 16 + hi * 4;
#pragma unroll
        for (int r = 0; r < 4; ++r) outf[(size_t)(m0 + r) * N + col] = acc[mf][nf][r] + bv;
      }
    }
  }
}

// ---------------- causal flash attention ----------------
// grid (8 q-tiles, 96 bh); 4 waves; wave owns 32 q rows. KVBLK=64.
// K/V/P LDS rows are 128B -> XOR swizzle byte^=((row&7)<<4) on both sides
// (inverse-swizzled global source for global_load_lds, swizzled ds_read).
__global__ __launch_bounds__(256) void attn_kernel(
    const u16* __restrict__ Q, const u16* __restrict__ Kg,
    const u16* __restrict__ Vt, u16* __restrict__ Y) {
  __shared__ __align__(16) u16 Ks[64 * 64];
  __shared__ __align__(16) u16 Vs[64 * 64];
  __shared__ __align__(16) u16 Ps[4][32 * 64];
  const int tid = threadIdx.x;
  const int w = tid >> 6, l = tid & 63;
  const int lo = l & 15, hi = l >> 4;
  const int bh = blockIdx.y;
  const int b = bh / 12, h = bh % 12;
  const int qbase = blockIdx.x * 128;
  const int wq = qbase + w * 32;
  const float c1 = 0.125f * 1.44269504f;  // scale * log2(e)

  // Q fragments (A-operand): lane holds Q[wq+mq*16+lo][ks*32+hi*8 .. +7]
  bf16x8 qf[2][2];
  const u16* Qb = Q + (size_t)bh * 1024 * 64;
#pragma unroll
  for (int mq = 0; mq < 2; ++mq)
#pragma unroll
    for (int ks = 0; ks < 2; ++ks)
      qf[mq][ks] = ldf(Qb + (size_t)(wq + mq * 16 + lo) * 64 + ks * 32 + hi * 8);

  f32x4 o[2][4] = {};
  f32x4 mrow[2], lrow[2];
#pragma unroll
  for (int mq = 0; mq < 2; ++mq)
#pragma unroll
    for (int r = 0; r < 4; ++r) { mrow[mq][r] = -1e30f; lrow[mq][r] = 0.0f; }

  const int nkv = (qbase + 128) >> 6;
  const int qmax = wq + 31;
  const char* Kbp = (const char*)Kg + (size_t)bh * 1024 * 128;
  const char* Vbp = (const char*)Vt + (size_t)bh * 64 * 2048;
  const int swl = (lo & 7) << 4;

  for (int kt = 0; kt < nkv; ++kt) {
    const int kb = kt * 64;
    __syncthreads();
#pragma unroll
    for (int i = 0; i < 2; ++i) {
      int c = w * 2 + i;
      int row = c * 8 + (l >> 3);  // 8 rows (128B) per 1KB chunk
      int cb = ((l & 7) * 16) ^ ((row & 7) << 4);  // inverse-swizzled source
      gl_lds16(Kbp + (size_t)(kb + row) * 128 + cb, (char*)Ks + c * 1024);
      gl_lds16(Vbp + (size_t)row * 2048 + (size_t)kb * 2 + cb, (char*)Vs + c * 1024);
    }
    __syncthreads();
    if (kb > qmax) continue;  // fully masked for this wave (barriers already matched)

    // S = Q K^T  (D row = q, col = k)
    f32x4 s[2][4] = {};
#pragma unroll
    for (int kf = 0; kf < 4; ++kf) {
      int rb = (kf * 16 + lo) * 128;
#pragma unroll
      for (int ks = 0; ks < 2; ++ks) {
        bf16x8 kfr = ldf((const char*)Ks + rb + ((ks * 64 + hi * 16) ^ swl));
        s[0][kf] = MFMA16(qf[0][ks], kfr, s[0][kf]);
        s[1][kf] = MFMA16(qf[1][ks], kfr, s[1][kf]);
      }
    }
    // causal mask
    if (kb + 63 > wq) {
#pragma unroll
      for (int mq = 0; mq < 2; ++mq)
#pragma unroll
        for (int kf = 0; kf < 4; ++kf)
#pragma unroll
          for (int r = 0; r < 4; ++r) {
            int qrow = wq + mq * 16 + hi * 4 + r;
            int kcol = kb + kf * 16 + lo;
            if (kcol > qrow) s[mq][kf][r] = -1e30f;
          }
    }
    // online softmax (row = q lives on (hi,reg); 16 lo-lanes share the row)
    char* pw = (char*)&Ps[w][0];
#pragma unroll
    for (int mq = 0; mq < 2; ++mq) {
      f32x4 mx = s[mq][0];
#pragma unroll
      for (int kf = 1; kf < 4; ++kf)
#pragma unroll
        for (int r = 0; r < 4; ++r) mx[r] = fmaxf(mx[r], s[mq][kf][r]);
#pragma unroll
      for (int st = 1; st < 16; st <<= 1)
#pragma unroll
        for (int r = 0; r < 4; ++r) mx[r] = fmaxf(mx[r], __shfl_xor(mx[r], st));
      f32x4 al;
#pragma unroll
      for (int r = 0; r < 4; ++r) {
        float Mn = fmaxf(mrow[mq][r], mx[r] * c1);
        al[r] = exp2f(mrow[mq][r] - Mn);
        mrow[mq][r] = Mn;
      }
      f32x4 rs = {0.f, 0.f, 0.f, 0.f};
#pragma unroll
      for (int kf = 0; kf < 4; ++kf)
#pragma unroll
        for (int r = 0; r < 4; ++r) {
          float p = exp2f(fmaf(s[mq][kf][r], c1, -mrow[mq][r]));
          s[mq][kf][r] = p;
          rs[r] += p;
        }
#pragma unroll
      for (int st = 1; st < 16; st <<= 1)
#pragma unroll
        for (int r = 0; r < 4; ++r) rs[r] += __shfl_xor(rs[r], st);
#pragma unroll
      for (int r = 0; r < 4; ++r) lrow[mq][r] = lrow[mq][r] * al[r] + rs[r];
#pragma unroll
      for (int nd = 0; nd < 4; ++nd)
#pragma unroll
        for (int r = 0; r < 4; ++r) o[mq][nd][r] *= al[r];
      // store P (bf16) to per-wave LDS, swizzled
#pragma unroll
      for (int kf = 0; kf < 4; ++kf)
#pragma unroll
        for (int r = 0; r < 4; ++r) {
          int qrow = mq * 16 + hi * 4 + r;
          int cb = ((lo + kf * 16) * 2) ^ ((qrow & 7) << 4);
          *(u16*)(pw + qrow * 128 + cb) = f2b(s[mq][kf][r]);
        }
    }
    // PV: O[q][d] += P[q][k] V[k][d]
    bf16x8 pa[2][2];
#pragma unroll
    for (int mq = 0; mq < 2; ++mq)
#pragma unroll
      for (int ks = 0; ks < 2; ++ks)
        pa[mq][ks] = ldf(pw + (mq * 16 + lo) * 128 + ((ks * 64 + hi * 16) ^ swl));
#pragma unroll
    for (int nd = 0; nd < 4; ++nd) {
      int rb = (nd * 16 + lo) * 128;
#pragma unroll
      for (int ks = 0; ks < 2; ++ks) {
        bf16x8 vb = ldf((const char*)Vs + rb + ((ks * 64 + hi * 16) ^ swl));
        o[0][nd] = MFMA16(pa[0][ks], vb, o[0][nd]);
        o[1][nd] = MFMA16(pa[1][ks], vb, o[1][nd]);
      }
    }
  }

  // epilogue: y[b][t][h*64+d] bf16
#pragma unroll
  for (int mq = 0; mq < 2; ++mq) {
    f32x4 inv;
#pragma unroll
    for (int r = 0; r < 4; ++r) inv[r] = 1.0f / lrow[mq][r];
#pragma unroll
    for (int nd = 0; nd < 4; ++nd)
#pragma unroll
      for (int r = 0; r < 4; ++r) {
        int t = wq + mq * 16 + hi * 4 + r;
        int d = nd * 16 + lo;
        Y[((size_t)b * 1024 + t) * 768 + h * 64 + d] = f2b(o[mq][nd][r] * inv[r]);
      }
  }
}

// ---------------- launcher ----------------
extern "C" void kernel_launch(void* const* d_in, const int* in_sizes, int n_in,
                              void* d_out, int out_size, void* d_ws, size_t ws_size,
                              hipStream_t stream) {
  const float* x  = (const float*)d_in[0];
  const float* Wa = (const float*)d_in[1];
  const float* ba = (const float*)d_in[2];
  const float* Wp = (const float*)d_in[3];
  const float* bp = (const float*)d_in[4];
  float* out = (float*)d_out;
  char* ws = (char*)d_ws;

  constexpr size_t XB  = 0;                       // x bf16   [8192][768]
  constexpr size_t WAB = 12582912;                // W_attn bf16 [2304][768]
  constexpr size_t WPB = WAB + 3538944;           // W_proj bf16 [768][768]
  constexpr size_t QS  = WPB + 1179648;           // q bf16 [96][1024][64]
  constexpr size_t KS  = QS + 12582912;           // k bf16 [96][1024][64]
  constexpr size_t VTS = KS + 12582912;           // v^T bf16 [96][64][1024]
  constexpr size_t YB  = VTS + 12582912;          // y bf16 [8192][768]

  u16* xb  = (u16*)(ws + XB);
  u16* wab = (u16*)(ws + WAB);
  u16* wpb = (u16*)(ws + WPB);
  u16* qs  = (u16*)(ws + QS);
  u16* ks  = (u16*)(ws + KS);
  u16* vts = (u16*)(ws + VTS);
  u16* yb  = (u16*)(ws + YB);

  cvt_kernel<<<2048, 256, 0, stream>>>((const float4*)x,  (ushort4*)xb,  8192 * 768 / 4);
  cvt_kernel<<<1024, 256, 0, stream>>>((const float4*)Wa, (ushort4*)wab, 2304 * 768 / 4);
  cvt_kernel<<<512,  256, 0, stream>>>((const float4*)Wp, (ushort4*)wpb, 768 * 768 / 4);

  gemm_bt<0><<<dim3(18, 64), 256, 0, stream>>>(xb, wab, ba, 8192, 2304, 768,
                                               qs, ks, vts, nullptr);
  attn_kernel<<<dim3(8, 96), 256, 0, stream>>>(qs, ks, vts, yb);
  gemm_bt<1><<<dim3(6, 64), 256, 0, stream>>>(yb, wpb, bp, 8192, 768, 768,
                                              nullptr, nullptr, nullptr, out);
}

// Round 2
// 187.367 us; speedup vs baseline: 1.0423x; 1.0423x over previous
//
#include <hip/hip_runtime.h>

typedef unsigned short u16;
typedef __attribute__((ext_vector_type(8))) __bf16 bf16x8;
typedef __attribute__((ext_vector_type(4))) float f32x4;
typedef __attribute__((ext_vector_type(4))) int i32x4;

#define MFMA16(a, b, c) __builtin_amdgcn_mfma_f32_16x16x32_bf16(a, b, c, 0, 0, 0)

__device__ __forceinline__ u16 f2b(float f) {
  __bf16 h = (__bf16)f;
  return __builtin_bit_cast(u16, h);
}

// global -> LDS direct (wave-uniform LDS base + lane*16; global addr per-lane)
__device__ __forceinline__ void gl_lds16(const void* g, void* l) {
  __builtin_amdgcn_global_load_lds(
      (const __attribute__((address_space(1))) void*)g,
      (__attribute__((address_space(3))) void*)l, 16, 0, 0);
}

__device__ __forceinline__ bf16x8 ldf(const void* p) {
  return __builtin_bit_cast(bf16x8, *(const i32x4*)p);
}

// ---------------- f32 -> bf16 convert ----------------
__global__ __launch_bounds__(256) void cvt_kernel(const float4* __restrict__ in,
                                                  ushort4* __restrict__ out, int n4) {
  for (int i = blockIdx.x * blockDim.x + threadIdx.x; i < n4; i += gridDim.x * blockDim.x) {
    float4 v = in[i];
    ushort4 o;
    o.x = f2b(v.x); o.y = f2b(v.y); o.z = f2b(v.z); o.w = f2b(v.w);
    out[i] = o;
  }
}

// ---------------- GEMM: C[m][n] = sum_k A[m][k]*B[n][k] (+bias) ----------------
// m97 structure: BM=BN=128, BK=32, 4 waves (2x2), global_load_lds width 16.
// EPI=0: QKV epilogue -> q_s/k_s [bh][t][64] bf16, v transposed -> vt_s [bh][64][t] bf16
// EPI=1: proj epilogue -> f32 out [m][N]
template <int EPI>
__global__ __launch_bounds__(256) void gemm_bt(
    const u16* __restrict__ A, const u16* __restrict__ B,
    const float* __restrict__ bias, int M, int N, int K,
    u16* __restrict__ q_s, u16* __restrict__ k_s, u16* __restrict__ vt_s,
    float* __restrict__ outf) {
  __shared__ __align__(16) u16 As[128 * 32];
  __shared__ __align__(16) u16 Bs[128 * 32];
  const int tid = threadIdx.x;
  const int w = tid >> 6, l = tid & 63;
  const int lo = l & 15, hi = l >> 4;
  const int wr = w >> 1, wc = w & 1;
  const int bm0 = blockIdx.y * 128, bn0 = blockIdx.x * 128;
  const size_t Kb = (size_t)K * 2;

  f32x4 acc[4][4] = {};
  const char* Ab = (const char*)A;
  const char* Bb = (const char*)B;

  for (int kt = 0; kt < K; kt += 32) {
    __syncthreads();  // previous iter's ds_reads done before overwrite
#pragma unroll
    for (int i = 0; i < 2; ++i) {
      int c = w * 2 + i;                 // chunk 0..7 (1KB each)
      int row = c * 16 + (l >> 2);       // 16 rows / chunk (64B rows)
      int colb = (l & 3) * 16;
      gl_lds16(Ab + (size_t)(bm0 + row) * Kb + (size_t)kt * 2 + colb, (char*)As + c * 1024);
      gl_lds16(Bb + (size_t)(bn0 + row) * Kb + (size_t)kt * 2 + colb, (char*)Bs + c * 1024);
    }
    __syncthreads();  // vmcnt(0) drain -> tiles ready
    bf16x8 bfr[4];
#pragma unroll
    for (int nf = 0; nf < 4; ++nf)
      bfr[nf] = ldf((const char*)Bs + (wc * 64 + nf * 16 + lo) * 64 + hi * 16);
#pragma unroll
    for (int mf = 0; mf < 4; ++mf) {
      bf16x8 afr = ldf((const char*)As + (wr * 64 + mf * 16 + lo) * 64 + hi * 16);
#pragma unroll
      for (int nf = 0; nf < 4; ++nf) acc[mf][nf] = MFMA16(afr, bfr[nf], acc[mf][nf]);
    }
  }

  // Epilogue. C/D layout: col = lo, row = hi*4 + reg (m89/m91-verified).
#pragma unroll
  for (int nf = 0; nf < 4; ++nf) {
    int col = bn0 + wc * 64 + nf * 16 + lo;
    float bv = bias[col];
    if (EPI == 0) {
      int seg = col / 768;           // 0=q 1=k 2=v (BN=128 divides 768 -> uniform/block)
      int cs = col - seg * 768;
      int h = cs >> 6, d = cs & 63;
      u16* dst = (seg == 0) ? q_s : k_s;
#pragma unroll
      for (int mf = 0; mf < 4; ++mf) {
        int m0 = bm0 + wr * 64 + mf * 16 + hi * 4;
        int bb = m0 >> 10, t0 = m0 & 1023;
        size_t bh = (size_t)(bb * 12 + h);
        if (seg < 2) {
#pragma unroll
          for (int r = 0; r < 4; ++r)
            dst[(bh * 1024 + t0 + r) * 64 + d] = f2b(acc[mf][nf][r] + bv);
        } else {  // v transposed: 4 consecutive t -> one 8B store
          ushort4 pk;
          pk.x = f2b(acc[mf][nf][0] + bv);
          pk.y = f2b(acc[mf][nf][1] + bv);
          pk.z = f2b(acc[mf][nf][2] + bv);
          pk.w = f2b(acc[mf][nf][3] + bv);
          *(ushort4*)&vt_s[(bh * 64 + d) * 1024 + t0] = pk;
        }
      }
    } else {
#pragma unroll
      for (int mf = 0; mf < 4; ++mf) {
        int m0 = bm0 + wr * 64 + mf * 16 + hi * 4;
#pragma unroll
        for (int r = 0; r < 4; ++r) outf[(size_t)(m0 + r) * N + col] = acc[mf][nf][r] + bv;
      }
    }
  }
}

// ---------------- causal flash attention, v2 ----------------
// Barrier-free. Wave = (bh, strip p, strip 63-p), strips of 16 q-rows ->
// uniform ~17 KV tiles per wave (causal load balance). K/V fragments read
// directly from global (L2/L3-resident: 256 KB per bh, 24 MB total).
// Only P goes through per-wave XOR-swizzled LDS. No __syncthreads at all.
__global__ __launch_bounds__(256) void attn_kernel(
    const u16* __restrict__ Q, const u16* __restrict__ Kg,
    const u16* __restrict__ Vt, u16* __restrict__ Y) {
  __shared__ __align__(16) u16 Ps[4][16 * 64];  // per-wave P [16 rows][64 cols]
  const int tid = threadIdx.x;
  const int w = tid >> 6, l = tid & 63;
  const int lo = l & 15, hi = l >> 4;
  const int bh = blockIdx.y;
  const int b = bh / 12, h = bh % 12;
  const int p = blockIdx.x * 4 + w;  // 0..31
  const float c1 = 0.125f * 1.44269504f;  // scale * log2(e)
  char* pw = (char*)&Ps[w][0];
  const int swl = (lo & 7) << 4;
  const u16* Qb = Q + (size_t)bh * 65536;
  const u16* Kb = Kg + (size_t)bh * 65536;
  const u16* Vb = Vt + (size_t)bh * 65536;  // [64][1024]

#pragma unroll
  for (int mem = 0; mem < 2; ++mem) {
    const int s = mem ? (63 - p) : p;
    const int q0 = s * 16;
    const int nt = (q0 >> 6) + 1;  // KV tiles of 64 covering [0, q0+16)

    // Q fragments: A-operand, row = lo, k = ks*32 + hi*8
    bf16x8 qf[2];
#pragma unroll
    for (int ks = 0; ks < 2; ++ks)
      qf[ks] = ldf(Qb + (size_t)(q0 + lo) * 64 + ks * 32 + hi * 8);

    f32x4 o[4] = {};
    f32x4 mrow, lrow;
#pragma unroll
    for (int r = 0; r < 4; ++r) { mrow[r] = -1e30f; lrow[r] = 0.0f; }

    for (int kt = 0; kt < nt; ++kt) {
      const int kb = kt * 64;
      // ---- QK^T: S[q=row][k=col], B-frags direct from global
      f32x4 sv[4] = {};
#pragma unroll
      for (int kf = 0; kf < 4; ++kf) {
        const u16* kr = Kb + (size_t)(kb + kf * 16 + lo) * 64;
#pragma unroll
        for (int ks = 0; ks < 2; ++ks)
          sv[kf] = MFMA16(qf[ks], ldf(kr + ks * 32 + hi * 8), sv[kf]);
      }
      // ---- V frags issued early: overlap global latency with softmax
      bf16x8 vb[4][2];
#pragma unroll
      for (int nd = 0; nd < 4; ++nd) {
        const u16* vr = Vb + (size_t)(nd * 16 + lo) * 1024 + kb;
#pragma unroll
        for (int ks = 0; ks < 2; ++ks) vb[nd][ks] = ldf(vr + ks * 32 + hi * 8);
      }
      // ---- causal mask (only last tile crosses the diagonal)
      if (kt == nt - 1) {
#pragma unroll
        for (int kf = 0; kf < 4; ++kf)
#pragma unroll
          for (int r = 0; r < 4; ++r) {
            int qrow = q0 + hi * 4 + r;
            int kcol = kb + kf * 16 + lo;
            if (kcol > qrow) sv[kf][r] = -1e30f;
          }
      }
      // ---- online softmax; row = (hi, r), 16 lo-lanes share a row
      f32x4 mx = sv[0];
#pragma unroll
      for (int kf = 1; kf < 4; ++kf)
#pragma unroll
        for (int r = 0; r < 4; ++r) mx[r] = fmaxf(mx[r], sv[kf][r]);
#pragma unroll
      for (int st = 1; st < 16; st <<= 1)
#pragma unroll
        for (int r = 0; r < 4; ++r) mx[r] = fmaxf(mx[r], __shfl_xor(mx[r], st));
      f32x4 al;
#pragma unroll
      for (int r = 0; r < 4; ++r) {
        float Mn = fmaxf(mrow[r], mx[r] * c1);
        al[r] = __builtin_amdgcn_exp2f(mrow[r] - Mn);
        mrow[r] = Mn;
      }
      f32x4 rs = {0.f, 0.f, 0.f, 0.f};
#pragma unroll
      for (int kf = 0; kf < 4; ++kf)
#pragma unroll
        for (int r = 0; r < 4; ++r) {
          float pv = __builtin_amdgcn_exp2f(fmaf(sv[kf][r], c1, -mrow[r]));
          sv[kf][r] = pv;
          rs[r] += pv;
        }
#pragma unroll
      for (int st = 1; st < 16; st <<= 1)
#pragma unroll
        for (int r = 0; r < 4; ++r) rs[r] += __shfl_xor(rs[r], st);
#pragma unroll
      for (int r = 0; r < 4; ++r) lrow[r] = lrow[r] * al[r] + rs[r];
#pragma unroll
      for (int nd = 0; nd < 4; ++nd)
#pragma unroll
        for (int r = 0; r < 4; ++r) o[nd][r] *= al[r];
      // ---- P -> per-wave LDS (swizzled), reload as A-frag
#pragma unroll
      for (int kf = 0; kf < 4; ++kf)
#pragma unroll
        for (int r = 0; r < 4; ++r) {
          int qrow = hi * 4 + r;
          int cb = ((lo + kf * 16) * 2) ^ ((qrow & 7) << 4);
          *(u16*)(pw + qrow * 128 + cb) = f2b(sv[kf][r]);
        }
      bf16x8 pa[2];
#pragma unroll
      for (int ks = 0; ks < 2; ++ks)
        pa[ks] = ldf(pw + lo * 128 + ((ks * 64 + hi * 16) ^ swl));
      // ---- PV
#pragma unroll
      for (int nd = 0; nd < 4; ++nd)
#pragma unroll
        for (int ks = 0; ks < 2; ++ks)
          o[nd] = MFMA16(pa[ks], vb[nd][ks], o[nd]);
    }

    // ---- epilogue: y[b][t][h*64+d] bf16
    f32x4 inv;
#pragma unroll
    for (int r = 0; r < 4; ++r) inv[r] = 1.0f / lrow[r];
#pragma unroll
    for (int nd = 0; nd < 4; ++nd)
#pragma unroll
      for (int r = 0; r < 4; ++r) {
        int t = q0 + hi * 4 + r;
        int d = nd * 16 + lo;
        Y[((size_t)b * 1024 + t) * 768 + h * 64 + d] = f2b(o[nd][r] * inv[r]);
      }
  }
}

// ---------------- launcher ----------------
extern "C" void kernel_launch(void* const* d_in, const int* in_sizes, int n_in,
                              void* d_out, int out_size, void* d_ws, size_t ws_size,
                              hipStream_t stream) {
  const float* x  = (const float*)d_in[0];
  const float* Wa = (const float*)d_in[1];
  const float* ba = (const float*)d_in[2];
  const float* Wp = (const float*)d_in[3];
  const float* bp = (const float*)d_in[4];
  float* out = (float*)d_out;
  char* ws = (char*)d_ws;

  constexpr size_t XB  = 0;                       // x bf16   [8192][768]
  constexpr size_t WAB = 12582912;                // W_attn bf16 [2304][768]
  constexpr size_t WPB = WAB + 3538944;           // W_proj bf16 [768][768]
  constexpr size_t QS  = WPB + 1179648;           // q bf16 [96][1024][64]
  constexpr size_t KS  = QS + 12582912;           // k bf16 [96][1024][64]
  constexpr size_t VTS = KS + 12582912;           // v^T bf16 [96][64][1024]
  constexpr size_t YB  = VTS + 12582912;          // y bf16 [8192][768]

  u16* xb  = (u16*)(ws + XB);
  u16* wab = (u16*)(ws + WAB);
  u16* wpb = (u16*)(ws + WPB);
  u16* qs  = (u16*)(ws + QS);
  u16* ks  = (u16*)(ws + KS);
  u16* vts = (u16*)(ws + VTS);
  u16* yb  = (u16*)(ws + YB);

  cvt_kernel<<<2048, 256, 0, stream>>>((const float4*)x,  (ushort4*)xb,  8192 * 768 / 4);
  cvt_kernel<<<1024, 256, 0, stream>>>((const float4*)Wa, (ushort4*)wab, 2304 * 768 / 4);
  cvt_kernel<<<512,  256, 0, stream>>>((const float4*)Wp, (ushort4*)wpb, 768 * 768 / 4);

  gemm_bt<0><<<dim3(18, 64), 256, 0, stream>>>(xb, wab, ba, 8192, 2304, 768,
                                               qs, ks, vts, nullptr);
  attn_kernel<<<dim3(8, 96), 256, 0, stream>>>(qs, ks, vts, yb);
  gemm_bt<1><<<dim3(6, 64), 256, 0, stream>>>(yb, wpb, bp, 8192, 768, 768,
                                              nullptr, nullptr, nullptr, out);
}

// Round 3
// 176.601 us; speedup vs baseline: 1.1058x; 1.0610x over previous
//
#include <hip/hip_runtime.h>

typedef unsigned short u16;
typedef __attribute__((ext_vector_type(8))) __bf16 bf16x8;
typedef __attribute__((ext_vector_type(4))) float f32x4;
typedef __attribute__((ext_vector_type(4))) int i32x4;

#define MFMA16(a, b, c) __builtin_amdgcn_mfma_f32_16x16x32_bf16(a, b, c, 0, 0, 0)

__device__ __forceinline__ u16 f2b(float f) {
  __bf16 h = (__bf16)f;
  return __builtin_bit_cast(u16, h);
}

// global -> LDS direct (wave-uniform LDS base + lane*16; global addr per-lane)
__device__ __forceinline__ void gl_lds16(const void* g, void* l) {
  __builtin_amdgcn_global_load_lds(
      (const __attribute__((address_space(1))) void*)g,
      (__attribute__((address_space(3))) void*)l, 16, 0, 0);
}

__device__ __forceinline__ bf16x8 ldf(const void* p) {
  return __builtin_bit_cast(bf16x8, *(const i32x4*)p);
}

// ---------------- f32 -> bf16 convert ----------------
__global__ __launch_bounds__(256) void cvt_kernel(const float4* __restrict__ in,
                                                  ushort4* __restrict__ out, int n4) {
  for (int i = blockIdx.x * blockDim.x + threadIdx.x; i < n4; i += gridDim.x * blockDim.x) {
    float4 v = in[i];
    ushort4 o;
    o.x = f2b(v.x); o.y = f2b(v.y); o.z = f2b(v.z); o.w = f2b(v.w);
    out[i] = o;
  }
}

// ---------------- GEMM: C[m][n] = sum_k A[m][k]*B[n][k] (+bias) ----------------
// m97 structure: BM=BN=128, BK=32, 4 waves (2x2), global_load_lds width 16.
// EPI=0: QKV epilogue -> q_s/k_s [bh][t][64] bf16, v transposed -> vt_s [bh][64][t] bf16
// EPI=1: proj epilogue -> f32 out [m][N]
template <int EPI>
__global__ __launch_bounds__(256) void gemm_bt(
    const u16* __restrict__ A, const u16* __restrict__ B,
    const float* __restrict__ bias, int M, int N, int K,
    u16* __restrict__ q_s, u16* __restrict__ k_s, u16* __restrict__ vt_s,
    float* __restrict__ outf) {
  __shared__ __align__(16) u16 As[128 * 32];
  __shared__ __align__(16) u16 Bs[128 * 32];
  const int tid = threadIdx.x;
  const int w = tid >> 6, l = tid & 63;
  const int lo = l & 15, hi = l >> 4;
  const int wr = w >> 1, wc = w & 1;
  const int bm0 = blockIdx.y * 128, bn0 = blockIdx.x * 128;
  const size_t Kb = (size_t)K * 2;

  f32x4 acc[4][4] = {};
  const char* Ab = (const char*)A;
  const char* Bb = (const char*)B;

  for (int kt = 0; kt < K; kt += 32) {
    __syncthreads();  // previous iter's ds_reads done before overwrite
#pragma unroll
    for (int i = 0; i < 2; ++i) {
      int c = w * 2 + i;                 // chunk 0..7 (1KB each)
      int row = c * 16 + (l >> 2);       // 16 rows / chunk (64B rows)
      int colb = (l & 3) * 16;
      gl_lds16(Ab + (size_t)(bm0 + row) * Kb + (size_t)kt * 2 + colb, (char*)As + c * 1024);
      gl_lds16(Bb + (size_t)(bn0 + row) * Kb + (size_t)kt * 2 + colb, (char*)Bs + c * 1024);
    }
    __syncthreads();  // vmcnt(0) drain -> tiles ready
    bf16x8 bfr[4];
#pragma unroll
    for (int nf = 0; nf < 4; ++nf)
      bfr[nf] = ldf((const char*)Bs + (wc * 64 + nf * 16 + lo) * 64 + hi * 16);
#pragma unroll
    for (int mf = 0; mf < 4; ++mf) {
      bf16x8 afr = ldf((const char*)As + (wr * 64 + mf * 16 + lo) * 64 + hi * 16);
#pragma unroll
      for (int nf = 0; nf < 4; ++nf) acc[mf][nf] = MFMA16(afr, bfr[nf], acc[mf][nf]);
    }
  }

  // Epilogue. C/D layout: col = lo, row = hi*4 + reg (m89/m91-verified).
#pragma unroll
  for (int nf = 0; nf < 4; ++nf) {
    int col = bn0 + wc * 64 + nf * 16 + lo;
    float bv = bias[col];
    if (EPI == 0) {
      int seg = col / 768;           // 0=q 1=k 2=v (BN=128 divides 768 -> uniform/block)
      int cs = col - seg * 768;
      int h = cs >> 6, d = cs & 63;
      u16* dst = (seg == 0) ? q_s : k_s;
#pragma unroll
      for (int mf = 0; mf < 4; ++mf) {
        int m0 = bm0 + wr * 64 + mf * 16 + hi * 4;
        int bb = m0 >> 10, t0 = m0 & 1023;
        size_t bh = (size_t)(bb * 12 + h);
        if (seg < 2) {
#pragma unroll
          for (int r = 0; r < 4; ++r)
            dst[(bh * 1024 + t0 + r) * 64 + d] = f2b(acc[mf][nf][r] + bv);
        } else {  // v transposed: 4 consecutive t -> one 8B store
          ushort4 pk;
          pk.x = f2b(acc[mf][nf][0] + bv);
          pk.y = f2b(acc[mf][nf][1] + bv);
          pk.z = f2b(acc[mf][nf][2] + bv);
          pk.w = f2b(acc[mf][nf][3] + bv);
          *(ushort4*)&vt_s[(bh * 64 + d) * 1024 + t0] = pk;
        }
      }
    } else {
#pragma unroll
      for (int mf = 0; mf < 4; ++mf) {
        int m0 = bm0 + wr * 64 + mf * 16 + hi * 4;
#pragma unroll
        for (int r = 0; r < 4; ++r) outf[(size_t)(m0 + r) * N + col] = acc[mf][nf][r] + bv;
      }
    }
  }
}

// ---------------- causal flash attention, v3 ----------------
// Block = one 64-row q-tile (4 waves x 16 q-rows, all sharing the same KV
// range -> LDS staging reused x4). Grid 16 x 96 = 1536 blocks (backfill
// smooths causal imbalance). K/V double-buffered in LDS via global_load_lds;
// counted s_waitcnt vmcnt(4) so the next tile's stage stays in flight across
// the barrier (T3/T4 minimum pipeline — never drain vmcnt to 0 in-loop).
// XOR swizzle byte^=((row&7)<<4): pre-swizzled global source + swizzled read.
__global__ __launch_bounds__(256) void attn_kernel(
    const u16* __restrict__ Q, const u16* __restrict__ Kg,
    const u16* __restrict__ Vt, u16* __restrict__ Y) {
  __shared__ __align__(16) u16 Ks[2][64 * 64];
  __shared__ __align__(16) u16 Vs[2][64 * 64];
  __shared__ __align__(16) u16 Ps[4][16 * 64];
  const int tid = threadIdx.x;
  const int w = tid >> 6, l = tid & 63;
  const int lo = l & 15, hi = l >> 4;
  const int bh = blockIdx.y;
  const int b = bh / 12, h = bh % 12;
  const int qt = blockIdx.x;           // 0..15, 64-row q-tile
  const int q0 = qt * 64 + w * 16;     // wave's 16 q-rows
  const int nt = qt + 1;               // KV tiles of 64
  const float c1 = 0.125f * 1.44269504f;  // scale * log2(e)
  char* pw = (char*)&Ps[w][0];
  const int swl = (lo & 7) << 4;
  const u16* Qb = Q + (size_t)bh * 65536;
  const char* Kbp = (const char*)(Kg + (size_t)bh * 65536);
  const char* Vbp = (const char*)(Vt + (size_t)bh * 65536);  // [64 d][1024 t]

  // Q fragments: A-operand, row = lo, k = ks*32 + hi*8
  bf16x8 qf[2];
#pragma unroll
  for (int ks = 0; ks < 2; ++ks)
    qf[ks] = ldf(Qb + (size_t)(q0 + lo) * 64 + ks * 32 + hi * 8);

  f32x4 o[4] = {};
  f32x4 mrow, lrow;
#pragma unroll
  for (int r = 0; r < 4; ++r) { mrow[r] = -1e30f; lrow[r] = 0.0f; }

  // Per-wave staging: 4 gl_lds16 (2 K chunks + 2 V chunks of 1KB).
  auto STAGE = [&](int buf, int kb) {
#pragma unroll
    for (int i = 0; i < 2; ++i) {
      int c = w * 2 + i;
      int row = c * 8 + (l >> 3);                    // 8 rows (128B) / chunk
      int cb = ((l & 7) * 16) ^ ((row & 7) << 4);    // inverse-swizzled source
      gl_lds16(Kbp + (size_t)(kb + row) * 128 + cb, (char*)&Ks[buf][0] + c * 1024);
      gl_lds16(Vbp + (size_t)row * 2048 + (size_t)kb * 2 + cb, (char*)&Vs[buf][0] + c * 1024);
    }
  };

  STAGE(0, 0);
  for (int kt = 0; kt < nt; ++kt) {
    const int cur = kt & 1;
    if (kt + 1 < nt) {
      STAGE(cur ^ 1, (kt + 1) * 64);
      asm volatile("s_waitcnt vmcnt(4)" ::: "memory");  // prev stage landed
    } else {
      asm volatile("s_waitcnt vmcnt(0)" ::: "memory");
    }
    __builtin_amdgcn_s_barrier();
    __builtin_amdgcn_sched_barrier(0);
    const char* Kt = (const char*)&Ks[cur][0];
    const char* Vv = (const char*)&Vs[cur][0];
    const int kb = kt * 64;

    // ---- QK^T: S[q=row][k=col]
    f32x4 sv[4] = {};
#pragma unroll
    for (int kf = 0; kf < 4; ++kf) {
      int rb = (kf * 16 + lo) * 128;
#pragma unroll
      for (int ks = 0; ks < 2; ++ks)
        sv[kf] = MFMA16(qf[ks], ldf(Kt + rb + ((ks * 64 + hi * 16) ^ swl)), sv[kf]);
    }
    // ---- causal mask (only diagonal tile crosses)
    if (kt == nt - 1) {
#pragma unroll
      for (int kf = 0; kf < 4; ++kf)
#pragma unroll
        for (int r = 0; r < 4; ++r) {
          int qrow = q0 + hi * 4 + r;
          int kcol = kb + kf * 16 + lo;
          if (kcol > qrow) sv[kf][r] = -1e30f;
        }
    }
    // ---- online softmax; row = (hi, r), 16 lo-lanes share a row
    f32x4 mx = sv[0];
#pragma unroll
    for (int kf = 1; kf < 4; ++kf)
#pragma unroll
      for (int r = 0; r < 4; ++r) mx[r] = fmaxf(mx[r], sv[kf][r]);
#pragma unroll
    for (int st = 1; st < 16; st <<= 1)
#pragma unroll
      for (int r = 0; r < 4; ++r) mx[r] = fmaxf(mx[r], __shfl_xor(mx[r], st));
    f32x4 al;
#pragma unroll
    for (int r = 0; r < 4; ++r) {
      float Mn = fmaxf(mrow[r], mx[r] * c1);
      al[r] = __builtin_amdgcn_exp2f(mrow[r] - Mn);
      mrow[r] = Mn;
    }
    f32x4 rs = {0.f, 0.f, 0.f, 0.f};
#pragma unroll
    for (int kf = 0; kf < 4; ++kf)
#pragma unroll
      for (int r = 0; r < 4; ++r) {
        float pv = __builtin_amdgcn_exp2f(fmaf(sv[kf][r], c1, -mrow[r]));
        sv[kf][r] = pv;
        rs[r] += pv;
      }
#pragma unroll
    for (int st = 1; st < 16; st <<= 1)
#pragma unroll
      for (int r = 0; r < 4; ++r) rs[r] += __shfl_xor(rs[r], st);
#pragma unroll
    for (int r = 0; r < 4; ++r) lrow[r] = lrow[r] * al[r] + rs[r];
#pragma unroll
    for (int nd = 0; nd < 4; ++nd)
#pragma unroll
      for (int r = 0; r < 4; ++r) o[nd][r] *= al[r];
    // ---- P -> per-wave LDS (swizzled), reload as A-frag
#pragma unroll
    for (int kf = 0; kf < 4; ++kf)
#pragma unroll
      for (int r = 0; r < 4; ++r) {
        int qrow = hi * 4 + r;
        int cb = ((lo + kf * 16) * 2) ^ ((qrow & 7) << 4);
        *(u16*)(pw + qrow * 128 + cb) = f2b(sv[kf][r]);
      }
    bf16x8 pa[2];
#pragma unroll
    for (int ks = 0; ks < 2; ++ks)
      pa[ks] = ldf(pw + lo * 128 + ((ks * 64 + hi * 16) ^ swl));
    // ---- PV: O[q][d] += P[q][k] V[k][d]  (Vs row = d, col = k)
#pragma unroll
    for (int nd = 0; nd < 4; ++nd) {
      int rb = (nd * 16 + lo) * 128;
#pragma unroll
      for (int ks = 0; ks < 2; ++ks)
        o[nd] = MFMA16(pa[ks], ldf(Vv + rb + ((ks * 64 + hi * 16) ^ swl)), o[nd]);
    }
    __builtin_amdgcn_sched_barrier(0);
    __builtin_amdgcn_s_barrier();  // all reads of `cur` done before re-stage
  }

  // ---- epilogue: y[b][t][h*64+d] bf16
  f32x4 inv;
#pragma unroll
  for (int r = 0; r < 4; ++r) inv[r] = 1.0f / lrow[r];
#pragma unroll
  for (int nd = 0; nd < 4; ++nd)
#pragma unroll
    for (int r = 0; r < 4; ++r) {
      int t = q0 + hi * 4 + r;
      int d = nd * 16 + lo;
      Y[((size_t)b * 1024 + t) * 768 + h * 64 + d] = f2b(o[nd][r] * inv[r]);
    }
}

// ---------------- launcher ----------------
extern "C" void kernel_launch(void* const* d_in, const int* in_sizes, int n_in,
                              void* d_out, int out_size, void* d_ws, size_t ws_size,
                              hipStream_t stream) {
  const float* x  = (const float*)d_in[0];
  const float* Wa = (const float*)d_in[1];
  const float* ba = (const float*)d_in[2];
  const float* Wp = (const float*)d_in[3];
  const float* bp = (const float*)d_in[4];
  float* out = (float*)d_out;
  char* ws = (char*)d_ws;

  constexpr size_t XB  = 0;                       // x bf16   [8192][768]
  constexpr size_t WAB = 12582912;                // W_attn bf16 [2304][768]
  constexpr size_t WPB = WAB + 3538944;           // W_proj bf16 [768][768]
  constexpr size_t QS  = WPB + 1179648;           // q bf16 [96][1024][64]
  constexpr size_t KS  = QS + 12582912;           // k bf16 [96][1024][64]
  constexpr size_t VTS = KS + 12582912;           // v^T bf16 [96][64][1024]
  constexpr size_t YB  = VTS + 12582912;          // y bf16 [8192][768]

  u16* xb  = (u16*)(ws + XB);
  u16* wab = (u16*)(ws + WAB);
  u16* wpb = (u16*)(ws + WPB);
  u16* qs  = (u16*)(ws + QS);
  u16* ks  = (u16*)(ws + KS);
  u16* vts = (u16*)(ws + VTS);
  u16* yb  = (u16*)(ws + YB);

  cvt_kernel<<<2048, 256, 0, stream>>>((const float4*)x,  (ushort4*)xb,  8192 * 768 / 4);
  cvt_kernel<<<1024, 256, 0, stream>>>((const float4*)Wa, (ushort4*)wab, 2304 * 768 / 4);
  cvt_kernel<<<512,  256, 0, stream>>>((const float4*)Wp, (ushort4*)wpb, 768 * 768 / 4);

  gemm_bt<0><<<dim3(18, 64), 256, 0, stream>>>(xb, wab, ba, 8192, 2304, 768,
                                               qs, ks, vts, nullptr);
  attn_kernel<<<dim3(16, 96), 256, 0, stream>>>(qs, ks, vts, yb);
  gemm_bt<1><<<dim3(6, 64), 256, 0, stream>>>(yb, wpb, bp, 8192, 768, 768,
                                              nullptr, nullptr, nullptr, out);
}

// Round 4
// 138.393 us; speedup vs baseline: 1.4111x; 1.2761x over previous
//
#include <hip/hip_runtime.h>

typedef unsigned short u16;
typedef __attribute__((ext_vector_type(8))) __bf16 bf16x8;
typedef __attribute__((ext_vector_type(4))) float f32x4;
typedef __attribute__((ext_vector_type(4))) int i32x4;

#define MFMA16(a, b, c) __builtin_amdgcn_mfma_f32_16x16x32_bf16(a, b, c, 0, 0, 0)

__device__ __forceinline__ u16 f2b(float f) {
  __bf16 h = (__bf16)f;
  return __builtin_bit_cast(u16, h);
}

// global -> LDS direct (wave-uniform LDS base + lane*16; global addr per-lane)
__device__ __forceinline__ void gl_lds16(const void* g, void* l) {
  __builtin_amdgcn_global_load_lds(
      (const __attribute__((address_space(1))) void*)g,
      (__attribute__((address_space(3))) void*)l, 16, 0, 0);
}

__device__ __forceinline__ bf16x8 ldf(const void* p) {
  return __builtin_bit_cast(bf16x8, *(const i32x4*)p);
}

// ---------------- f32 -> bf16 convert ----------------
__global__ __launch_bounds__(256) void cvt_kernel(const float4* __restrict__ in,
                                                  ushort4* __restrict__ out, int n4) {
  for (int i = blockIdx.x * blockDim.x + threadIdx.x; i < n4; i += gridDim.x * blockDim.x) {
    float4 v = in[i];
    ushort4 o;
    o.x = f2b(v.x); o.y = f2b(v.y); o.z = f2b(v.z); o.w = f2b(v.w);
    out[i] = o;
  }
}

// ---------------- GEMM: C[m][n] = sum_k A[m][k]*B[n][k] (+bias) ----------------
// m97 structure: BM=BN=128, BK=32, 4 waves (2x2), global_load_lds width 16.
// EPI=0: QKV epilogue -> q_s/k_s [bh][t][64] bf16, v transposed -> vt_s [bh][64][t] bf16
// EPI=1: proj epilogue -> f32 out [m][N]
template <int EPI>
__global__ __launch_bounds__(256) void gemm_bt(
    const u16* __restrict__ A, const u16* __restrict__ B,
    const float* __restrict__ bias, int M, int N, int K,
    u16* __restrict__ q_s, u16* __restrict__ k_s, u16* __restrict__ vt_s,
    float* __restrict__ outf) {
  __shared__ __align__(16) u16 As[128 * 32];
  __shared__ __align__(16) u16 Bs[128 * 32];
  const int tid = threadIdx.x;
  const int w = tid >> 6, l = tid & 63;
  const int lo = l & 15, hi = l >> 4;
  const int wr = w >> 1, wc = w & 1;
  const int bm0 = blockIdx.y * 128, bn0 = blockIdx.x * 128;
  const size_t Kb = (size_t)K * 2;

  f32x4 acc[4][4] = {};
  const char* Ab = (const char*)A;
  const char* Bb = (const char*)B;

  for (int kt = 0; kt < K; kt += 32) {
    __syncthreads();  // previous iter's ds_reads done before overwrite
#pragma unroll
    for (int i = 0; i < 2; ++i) {
      int c = w * 2 + i;                 // chunk 0..7 (1KB each)
      int row = c * 16 + (l >> 2);       // 16 rows / chunk (64B rows)
      int colb = (l & 3) * 16;
      gl_lds16(Ab + (size_t)(bm0 + row) * Kb + (size_t)kt * 2 + colb, (char*)As + c * 1024);
      gl_lds16(Bb + (size_t)(bn0 + row) * Kb + (size_t)kt * 2 + colb, (char*)Bs + c * 1024);
    }
    __syncthreads();  // vmcnt(0) drain -> tiles ready
    bf16x8 bfr[4];
#pragma unroll
    for (int nf = 0; nf < 4; ++nf)
      bfr[nf] = ldf((const char*)Bs + (wc * 64 + nf * 16 + lo) * 64 + hi * 16);
#pragma unroll
    for (int mf = 0; mf < 4; ++mf) {
      bf16x8 afr = ldf((const char*)As + (wr * 64 + mf * 16 + lo) * 64 + hi * 16);
#pragma unroll
      for (int nf = 0; nf < 4; ++nf) acc[mf][nf] = MFMA16(afr, bfr[nf], acc[mf][nf]);
    }
  }

  // Epilogue. C/D layout: col = lo, row = hi*4 + reg (m89/m91-verified).
#pragma unroll
  for (int nf = 0; nf < 4; ++nf) {
    int col = bn0 + wc * 64 + nf * 16 + lo;
    float bv = bias[col];
    if (EPI == 0) {
      int seg = col / 768;           // 0=q 1=k 2=v (BN=128 divides 768 -> uniform/block)
      int cs = col - seg * 768;
      int h = cs >> 6, d = cs & 63;
      u16* dst = (seg == 0) ? q_s : k_s;
#pragma unroll
      for (int mf = 0; mf < 4; ++mf) {
        int m0 = bm0 + wr * 64 + mf * 16 + hi * 4;
        int bb = m0 >> 10, t0 = m0 & 1023;
        size_t bh = (size_t)(bb * 12 + h);
        if (seg < 2) {
#pragma unroll
          for (int r = 0; r < 4; ++r)
            dst[(bh * 1024 + t0 + r) * 64 + d] = f2b(acc[mf][nf][r] + bv);
        } else {  // v transposed: 4 consecutive t -> one 8B store
          ushort4 pk;
          pk.x = f2b(acc[mf][nf][0] + bv);
          pk.y = f2b(acc[mf][nf][1] + bv);
          pk.z = f2b(acc[mf][nf][2] + bv);
          pk.w = f2b(acc[mf][nf][3] + bv);
          *(ushort4*)&vt_s[(bh * 64 + d) * 1024 + t0] = pk;
        }
      }
    } else {
#pragma unroll
      for (int mf = 0; mf < 4; ++mf) {
        int m0 = bm0 + wr * 64 + mf * 16 + hi * 4;
#pragma unroll
        for (int r = 0; r < 4; ++r) outf[(size_t)(m0 + r) * N + col] = acc[mf][nf][r] + bv;
      }
    }
  }
}

// ---------------- causal flash attention, v4 ----------------
// Block = tile PAIR {p, 15-p}: two sequential 64-row q-tile segments ->
// exactly 17 KV-tile iterations per block (causal-uniform). Grid 8 x 96 =
// 768 blocks, 3/CU, all co-resident, no tail. K/V double-buffered in LDS
// (global_load_lds, counted vmcnt(4) — T3/T4 minimum). Defer-max (T13,
// THR=8 in log2 units): skip max-tree + rescale unless some lane's local
// max exceeds the running max by >THR.
__global__ __launch_bounds__(256) void attn_kernel(
    const u16* __restrict__ Q, const u16* __restrict__ Kg,
    const u16* __restrict__ Vt, u16* __restrict__ Y) {
  __shared__ __align__(16) u16 Ks[2][64 * 64];
  __shared__ __align__(16) u16 Vs[2][64 * 64];
  __shared__ __align__(16) u16 Ps[4][16 * 64];
  const int tid = threadIdx.x;
  const int w = tid >> 6, l = tid & 63;
  const int lo = l & 15, hi = l >> 4;
  const int bh = blockIdx.y;
  const int b = bh / 12, h = bh % 12;
  const int pr = blockIdx.x;  // 0..7 -> tiles {pr, 15-pr}
  const float c1 = 0.125f * 1.44269504f;  // scale * log2(e)
  char* pw = (char*)&Ps[w][0];
  const int swl = (lo & 7) << 4;
  const u16* Qb = Q + (size_t)bh * 65536;
  const char* Kbp = (const char*)(Kg + (size_t)bh * 65536);
  const char* Vbp = (const char*)(Vt + (size_t)bh * 65536);  // [64 d][1024 t]

  // Per-wave staging: 4 gl_lds16 (2 K chunks + 2 V chunks of 1KB).
  auto STAGE = [&](int buf, int kb) {
#pragma unroll
    for (int i = 0; i < 2; ++i) {
      int c = w * 2 + i;
      int row = c * 8 + (l >> 3);                    // 8 rows (128B) / chunk
      int cb = ((l & 7) * 16) ^ ((row & 7) << 4);    // inverse-swizzled source
      gl_lds16(Kbp + (size_t)(kb + row) * 128 + cb, (char*)&Ks[buf][0] + c * 1024);
      gl_lds16(Vbp + (size_t)row * 2048 + (size_t)kb * 2 + cb, (char*)&Vs[buf][0] + c * 1024);
    }
  };

  for (int sg = 0; sg < 2; ++sg) {
    const int tile = sg ? (15 - pr) : pr;
    const int q0 = tile * 64 + w * 16;  // wave's 16 q-rows
    const int nt = tile + 1;            // KV tiles of 64

    // Q fragments: A-operand, row = lo, k = ks*32 + hi*8
    bf16x8 qf[2];
#pragma unroll
    for (int ks = 0; ks < 2; ++ks)
      qf[ks] = ldf(Qb + (size_t)(q0 + lo) * 64 + ks * 32 + hi * 8);

    f32x4 o[4] = {};
    f32x4 mrow, lrow;
#pragma unroll
    for (int r = 0; r < 4; ++r) { mrow[r] = -1e30f; lrow[r] = 0.0f; }

    STAGE(0, 0);
    for (int kt = 0; kt < nt; ++kt) {
      const int cur = kt & 1;
      if (kt + 1 < nt) {
        STAGE(cur ^ 1, (kt + 1) * 64);
        asm volatile("s_waitcnt vmcnt(4)" ::: "memory");  // prev stage landed
      } else {
        asm volatile("s_waitcnt vmcnt(0)" ::: "memory");
      }
      __builtin_amdgcn_s_barrier();
      __builtin_amdgcn_sched_barrier(0);
      const char* Kt = (const char*)&Ks[cur][0];
      const char* Vv = (const char*)&Vs[cur][0];
      const int kb = kt * 64;

      // ---- QK^T: S[q=row][k=col]
      f32x4 sv[4] = {};
#pragma unroll
      for (int kf = 0; kf < 4; ++kf) {
        int rb = (kf * 16 + lo) * 128;
#pragma unroll
        for (int ks = 0; ks < 2; ++ks)
          sv[kf] = MFMA16(qf[ks], ldf(Kt + rb + ((ks * 64 + hi * 16) ^ swl)), sv[kf]);
      }
      // ---- causal mask (only diagonal tile crosses)
      if (kt == nt - 1) {
#pragma unroll
        for (int kf = 0; kf < 4; ++kf)
#pragma unroll
          for (int r = 0; r < 4; ++r) {
            int qrow = q0 + hi * 4 + r;
            int kcol = kb + kf * 16 + lo;
            if (kcol > qrow) sv[kf][r] = -1e30f;
          }
      }
      // ---- online softmax with defer-max (row = (hi,r); 16 lo-lanes/row)
      f32x4 lm = sv[0];
#pragma unroll
      for (int kf = 1; kf < 4; ++kf)
#pragma unroll
        for (int r = 0; r < 4; ++r) lm[r] = fmaxf(lm[r], sv[kf][r]);
      bool need = false;
#pragma unroll
      for (int r = 0; r < 4; ++r) need |= (lm[r] * c1 > mrow[r] + 8.0f);
      if (__any(need)) {
#pragma unroll
        for (int st = 1; st < 16; st <<= 1)
#pragma unroll
          for (int r = 0; r < 4; ++r) lm[r] = fmaxf(lm[r], __shfl_xor(lm[r], st));
        f32x4 al;
#pragma unroll
        for (int r = 0; r < 4; ++r) {
          float Mn = fmaxf(mrow[r], lm[r] * c1);
          al[r] = __builtin_amdgcn_exp2f(mrow[r] - Mn);
          mrow[r] = Mn;
          lrow[r] *= al[r];
        }
#pragma unroll
        for (int nd = 0; nd < 4; ++nd)
#pragma unroll
          for (int r = 0; r < 4; ++r) o[nd][r] *= al[r];
      }
      f32x4 rs = {0.f, 0.f, 0.f, 0.f};
#pragma unroll
      for (int kf = 0; kf < 4; ++kf)
#pragma unroll
        for (int r = 0; r < 4; ++r) {
          float pv = __builtin_amdgcn_exp2f(fmaf(sv[kf][r], c1, -mrow[r]));
          sv[kf][r] = pv;
          rs[r] += pv;
        }
#pragma unroll
      for (int st = 1; st < 16; st <<= 1)
#pragma unroll
        for (int r = 0; r < 4; ++r) rs[r] += __shfl_xor(rs[r], st);
#pragma unroll
      for (int r = 0; r < 4; ++r) lrow[r] += rs[r];
      // ---- P -> per-wave LDS (swizzled), reload as A-frag
#pragma unroll
      for (int kf = 0; kf < 4; ++kf)
#pragma unroll
        for (int r = 0; r < 4; ++r) {
          int qrow = hi * 4 + r;
          int cb = ((lo + kf * 16) * 2) ^ ((qrow & 7) << 4);
          *(u16*)(pw + qrow * 128 + cb) = f2b(sv[kf][r]);
        }
      bf16x8 pa[2];
#pragma unroll
      for (int ks = 0; ks < 2; ++ks)
        pa[ks] = ldf(pw + lo * 128 + ((ks * 64 + hi * 16) ^ swl));
      // ---- PV: O[q][d] += P[q][k] V[k][d]  (Vs row = d, col = k)
#pragma unroll
      for (int nd = 0; nd < 4; ++nd) {
        int rb = (nd * 16 + lo) * 128;
#pragma unroll
        for (int ks = 0; ks < 2; ++ks)
          o[nd] = MFMA16(pa[ks], ldf(Vv + rb + ((ks * 64 + hi * 16) ^ swl)), o[nd]);
      }
      __builtin_amdgcn_sched_barrier(0);
      __builtin_amdgcn_s_barrier();  // all reads of `cur` done before re-stage
    }

    // ---- epilogue: y[b][t][h*64+d] bf16
    f32x4 inv;
#pragma unroll
    for (int r = 0; r < 4; ++r) inv[r] = 1.0f / lrow[r];
#pragma unroll
    for (int nd = 0; nd < 4; ++nd)
#pragma unroll
      for (int r = 0; r < 4; ++r) {
        int t = q0 + hi * 4 + r;
        int d = nd * 16 + lo;
        Y[((size_t)b * 1024 + t) * 768 + h * 64 + d] = f2b(o[nd][r] * inv[r]);
      }
  }
}

// ---------------- launcher ----------------
extern "C" void kernel_launch(void* const* d_in, const int* in_sizes, int n_in,
                              void* d_out, int out_size, void* d_ws, size_t ws_size,
                              hipStream_t stream) {
  const float* x  = (const float*)d_in[0];
  const float* Wa = (const float*)d_in[1];
  const float* ba = (const float*)d_in[2];
  const float* Wp = (const float*)d_in[3];
  const float* bp = (const float*)d_in[4];
  float* out = (float*)d_out;
  char* ws = (char*)d_ws;

  constexpr size_t XB  = 0;                       // x bf16   [8192][768]
  constexpr size_t WAB = 12582912;                // W_attn bf16 [2304][768]
  constexpr size_t WPB = WAB + 3538944;           // W_proj bf16 [768][768]
  constexpr size_t QS  = WPB + 1179648;           // q bf16 [96][1024][64]
  constexpr size_t KS  = QS + 12582912;           // k bf16 [96][1024][64]
  constexpr size_t VTS = KS + 12582912;           // v^T bf16 [96][64][1024]
  constexpr size_t YB  = VTS + 12582912;          // y bf16 [8192][768]

  u16* xb  = (u16*)(ws + XB);
  u16* wab = (u16*)(ws + WAB);
  u16* wpb = (u16*)(ws + WPB);
  u16* qs  = (u16*)(ws + QS);
  u16* ks  = (u16*)(ws + KS);
  u16* vts = (u16*)(ws + VTS);
  u16* yb  = (u16*)(ws + YB);

  cvt_kernel<<<2048, 256, 0, stream>>>((const float4*)x,  (ushort4*)xb,  8192 * 768 / 4);
  cvt_kernel<<<1024, 256, 0, stream>>>((const float4*)Wa, (ushort4*)wab, 2304 * 768 / 4);
  cvt_kernel<<<512,  256, 0, stream>>>((const float4*)Wp, (ushort4*)wpb, 768 * 768 / 4);

  gemm_bt<0><<<dim3(18, 64), 256, 0, stream>>>(xb, wab, ba, 8192, 2304, 768,
                                               qs, ks, vts, nullptr);
  attn_kernel<<<dim3(8, 96), 256, 0, stream>>>(qs, ks, vts, yb);
  gemm_bt<1><<<dim3(6, 64), 256, 0, stream>>>(yb, wpb, bp, 8192, 768, 768,
                                              nullptr, nullptr, nullptr, out);
}